// Round 3
// baseline (296.538 us; speedup 1.0000x reference)
//
#include <hip/hip_runtime.h>
#include <math.h>

#define P_NUM 8192
#define E_NUM 4194304
#define EPT 8

#define FOV_H 2.0943951f

typedef float f32x4 __attribute__((ext_vector_type(4)));
typedef float f32x2 __attribute__((ext_vector_type(2)));
typedef int   i32x4 __attribute__((ext_vector_type(4)));

// ---------- prep: one record per thread, every access coalesced.
// fused[t] = (vx,vy,vz,0) local cartesian; elev residual scalar;
// pose8 padding + pose residual folded into low-index threads.
__global__ __launch_bounds__(256) void fuse_prep(const f32x2* __restrict__ patch_coords,
                                                 const float* __restrict__ elev,
                                                 const float* __restrict__ init_elev,
                                                 const float* __restrict__ poses,
                                                 const float* __restrict__ init_poses,
                                                 f32x4* __restrict__ fused,
                                                 f32x4* __restrict__ pose8,
                                                 float* __restrict__ out) {
    const int t = blockIdx.x * blockDim.x + threadIdx.x;   // [0, E_NUM)

    const f32x2 pc = __builtin_nontemporal_load(patch_coords + t);   // (r, theta)
    const float e  = __builtin_nontemporal_load(elev + t);
    const float ie = __builtin_nontemporal_load(init_elev + t);

    const float r  = pc.x;
    const float th = pc.y;
    // identical op order to previous version
    const float cp = cosf(e),  sp = sinf(e);
    const float ct = cosf(th), st = sinf(th);
    const float rcp = r * cp;
    fused[t] = (f32x4){rcp * ct, rcp * st, r * sp, 0.0f};   // cached store: ba_main re-reads

    __builtin_nontemporal_store(e - ie, out + 2 * E_NUM + 7 * P_NUM + t);

    // pose work folded in: first P_NUM threads pad poses, first 14336 do residual
    if (t < P_NUM) {
        const float* s = poses + 7 * t;
        pose8[2 * t]     = (f32x4){s[0], s[1], s[2], s[3]};  // tx ty tz qx
        pose8[2 * t + 1] = (f32x4){s[4], s[5], s[6], 0.0f};  // qy qz qw pad
    }
    if (t < (7 * P_NUM) / 4) {
        const f32x4 pa = ((const f32x4*)poses)[t];
        const f32x4 pb = ((const f32x4*)init_poses)[t];
        const f32x4 r2 = {pa.x - pb.x, pa.y - pb.y, pa.z - pb.z, pa.w - pb.w};
        __builtin_nontemporal_store(r2, (f32x4*)(out + 2 * E_NUM) + t);
    }
}

__device__ __forceinline__ void quatrot(float ux, float uy, float uz, float uw,
                                        float vx, float vy, float vz,
                                        float& ox, float& oy, float& oz) {
    float tqx = 2.0f * (uy * vz - uz * vy);
    float tqy = 2.0f * (uz * vx - ux * vz);
    float tqz = 2.0f * (ux * vy - uy * vx);
    ox = vx + uw * tqx + (uy * tqz - uz * tqy);
    oy = vy + uw * tqy + (uz * tqx - ux * tqz);
    oz = vz + uw * tqz + (ux * tqy - uy * tqx);
}

__global__ __launch_bounds__(256) void ba_main(
    const f32x4* __restrict__ fused,   // E_NUM x (vx,vy,vz,pad), ws
    const f32x4* __restrict__ pose8,   // ws
    const float* __restrict__ target,  // E_NUM*2
    const int*   __restrict__ src_idx,
    const int*   __restrict__ tgt_idx,
    const int*   __restrict__ patch_idx,
    float*       __restrict__ out)
{
    const int tid = blockIdx.x * blockDim.x + threadIdx.x;  // [0, E_NUM/EPT)

    const float R_RANGE = 30.0f - 0.5f;
    const float BINS    = 512.0f;
    const float BEAMS   = 512.0f;

    // streaming index loads: non-temporal (don't evict the gather tables)
    const i32x4 s4a = __builtin_nontemporal_load((const i32x4*)src_idx + 2 * tid);
    const i32x4 s4b = __builtin_nontemporal_load((const i32x4*)src_idx + 2 * tid + 1);
    const i32x4 t4a = __builtin_nontemporal_load((const i32x4*)tgt_idx + 2 * tid);
    const i32x4 t4b = __builtin_nontemporal_load((const i32x4*)tgt_idx + 2 * tid + 1);
    const i32x4 p4a = __builtin_nontemporal_load((const i32x4*)patch_idx + 2 * tid);
    const i32x4 p4b = __builtin_nontemporal_load((const i32x4*)patch_idx + 2 * tid + 1);
    const int si[EPT] = {s4a.x, s4a.y, s4a.z, s4a.w, s4b.x, s4b.y, s4b.z, s4b.w};
    const int ti[EPT] = {t4a.x, t4a.y, t4a.z, t4a.w, t4b.x, t4b.y, t4b.z, t4b.w};
    const int pi[EPT] = {p4a.x, p4a.y, p4a.z, p4a.w, p4b.x, p4b.y, p4b.z, p4b.w};

    // ---- issue all gathers up front (fused first: longest latency) ----
    f32x4 rec[EPT];
    f32x4 slo[EPT], shi[EPT], tlo[EPT], thi[EPT];
#pragma unroll
    for (int e = 0; e < EPT; ++e) rec[e] = fused[pi[e]];
#pragma unroll
    for (int e = 0; e < EPT; ++e) {
        slo[e] = pose8[2 * si[e]];
        shi[e] = pose8[2 * si[e] + 1];
        tlo[e] = pose8[2 * ti[e]];
        thi[e] = pose8[2 * ti[e] + 1];
    }

    const f32x4 tg0 = __builtin_nontemporal_load((const f32x4*)target + 4 * tid);
    const f32x4 tg1 = __builtin_nontemporal_load((const f32x4*)target + 4 * tid + 1);
    const f32x4 tg2 = __builtin_nontemporal_load((const f32x4*)target + 4 * tid + 2);
    const f32x4 tg3 = __builtin_nontemporal_load((const f32x4*)target + 4 * tid + 3);
    const float tgr[EPT]  = {tg0.x, tg0.z, tg1.x, tg1.z, tg2.x, tg2.z, tg3.x, tg3.z};
    const float tgth[EPT] = {tg0.y, tg0.w, tg1.y, tg1.w, tg2.y, tg2.w, tg3.y, tg3.w};

    float res[2 * EPT];
#pragma unroll
    for (int e = 0; e < EPT; ++e) {
        // local cartesian already precomputed in prep
        const float vx = rec[e].x;
        const float vy = rec[e].y;
        const float vz = rec[e].z;

        float gx, gy, gz;
        quatrot(slo[e].w, shi[e].x, shi[e].y, shi[e].z, vx, vy, vz, gx, gy, gz);
        gx += slo[e].x; gy += slo[e].y; gz += slo[e].z;

        float lx, ly, lz;
        quatrot(-tlo[e].w, -thi[e].x, -thi[e].y, thi[e].z,
                gx - tlo[e].x, gy - tlo[e].y, gz - tlo[e].z, lx, ly, lz);

        const float rr  = sqrtf(lx * lx + ly * ly + lz * lz);
        const float tth = atan2f(ly, lx);
        res[2 * e]     = (rr  - tgr[e])  / R_RANGE * BINS;
        res[2 * e + 1] = (tth - tgth[e]) / FOV_H * BEAMS;
    }

    const f32x4 o0 = {res[0],  res[1],  res[2],  res[3]};
    const f32x4 o1 = {res[4],  res[5],  res[6],  res[7]};
    const f32x4 o2 = {res[8],  res[9],  res[10], res[11]};
    const f32x4 o3 = {res[12], res[13], res[14], res[15]};
    __builtin_nontemporal_store(o0, (f32x4*)out + 4 * tid);
    __builtin_nontemporal_store(o1, (f32x4*)out + 4 * tid + 1);
    __builtin_nontemporal_store(o2, (f32x4*)out + 4 * tid + 2);
    __builtin_nontemporal_store(o3, (f32x4*)out + 4 * tid + 3);
}

extern "C" void kernel_launch(void* const* d_in, const int* in_sizes, int n_in,
                              void* d_out, int out_size, void* d_ws, size_t ws_size,
                              hipStream_t stream) {
    const float* poses        = (const float*)d_in[0];
    const float* init_poses   = (const float*)d_in[1];
    const float* patch_coords = (const float*)d_in[2];
    const float* elev         = (const float*)d_in[3];
    const float* init_elev    = (const float*)d_in[4];
    const float* target       = (const float*)d_in[5];
    const int*   src_idx      = (const int*)d_in[6];
    const int*   tgt_idx      = (const int*)d_in[7];
    const int*   patch_idx    = (const int*)d_in[8];
    float*       out          = (float*)d_out;

    f32x4* fused = (f32x4*)d_ws;                                   // 67.1 MB
    f32x4* pose8 = (f32x4*)((char*)d_ws + (size_t)E_NUM * 16);     // 256 KB

    fuse_prep<<<E_NUM / 256, 256, 0, stream>>>((const f32x2*)patch_coords, elev,
                                               init_elev, poses, init_poses,
                                               fused, pose8, out);

    const int block = 256;
    const int grid  = E_NUM / (block * EPT);    // 2048
    ba_main<<<grid, block, 0, stream>>>(fused, pose8, target, src_idx, tgt_idx,
                                        patch_idx, out);
}

// Round 5
// 271.046 us; speedup vs baseline: 1.0940x; 1.0940x over previous
//
#include <hip/hip_runtime.h>
#include <math.h>

#define P_NUM 8192
#define E_NUM 4194304
#define EPT 4

#define FOV_H 2.0943951f

typedef float f32x4 __attribute__((ext_vector_type(4)));
typedef float f32x2 __attribute__((ext_vector_type(2)));
typedef int   i32x4 __attribute__((ext_vector_type(4)));

// ---------- prep: one record per thread, every access coalesced.
// fused[t] = (vx,vy,vz,0) local cartesian; elev residual scalar;
// pose8 padding + pose residual folded into low-index threads.
__global__ __launch_bounds__(256) void fuse_prep(const f32x2* __restrict__ patch_coords,
                                                 const float* __restrict__ elev,
                                                 const float* __restrict__ init_elev,
                                                 const float* __restrict__ poses,
                                                 const float* __restrict__ init_poses,
                                                 f32x4* __restrict__ fused,
                                                 f32x4* __restrict__ pose8,
                                                 float* __restrict__ out) {
    const int t = blockIdx.x * blockDim.x + threadIdx.x;   // [0, E_NUM)

    const f32x2 pc = __builtin_nontemporal_load(patch_coords + t);   // (r, theta)
    const float e  = __builtin_nontemporal_load(elev + t);
    const float ie = __builtin_nontemporal_load(init_elev + t);

    const float r  = pc.x;
    const float th = pc.y;
    // identical op order to previous version
    const float cp = cosf(e),  sp = sinf(e);
    const float ct = cosf(th), st = sinf(th);
    const float rcp = r * cp;
    fused[t] = (f32x4){rcp * ct, rcp * st, r * sp, 0.0f};   // cached store: ba_main re-reads

    __builtin_nontemporal_store(e - ie, out + 2 * E_NUM + 7 * P_NUM + t);

    // pose work folded in: first P_NUM threads pad poses, first 14336 do residual
    if (t < P_NUM) {
        const float* s = poses + 7 * t;
        pose8[2 * t]     = (f32x4){s[0], s[1], s[2], s[3]};  // tx ty tz qx
        pose8[2 * t + 1] = (f32x4){s[4], s[5], s[6], 0.0f};  // qy qz qw pad
    }
    if (t < (7 * P_NUM) / 4) {
        const f32x4 pa = ((const f32x4*)poses)[t];
        const f32x4 pb = ((const f32x4*)init_poses)[t];
        const f32x4 r2 = {pa.x - pb.x, pa.y - pb.y, pa.z - pb.z, pa.w - pb.w};
        __builtin_nontemporal_store(r2, (f32x4*)(out + 2 * E_NUM) + t);
    }
}

__device__ __forceinline__ void quatrot(float ux, float uy, float uz, float uw,
                                        float vx, float vy, float vz,
                                        float& ox, float& oy, float& oz) {
    float tqx = 2.0f * (uy * vz - uz * vy);
    float tqy = 2.0f * (uz * vx - ux * vz);
    float tqz = 2.0f * (ux * vy - uy * vx);
    ox = vx + uw * tqx + (uy * tqz - uz * tqy);
    oy = vy + uw * tqy + (uz * tqx - ux * tqz);
    oz = vz + uw * tqz + (ux * tqy - uy * tqx);
}

// launch_bounds(256, 1): min 1 wave/EU -> VGPR cap 512, letting the scheduler
// keep ALL per-wave gathers (4 fused + 16 pose + idx/target streams) in flight
// before the first s_waitcnt, instead of serializing at VGPR=36.
__global__ __launch_bounds__(256, 1) void ba_main(
    const f32x4* __restrict__ fused,   // E_NUM x (vx,vy,vz,pad), ws
    const f32x4* __restrict__ pose8,   // ws
    const float* __restrict__ target,  // E_NUM*2
    const int*   __restrict__ src_idx,
    const int*   __restrict__ tgt_idx,
    const int*   __restrict__ patch_idx,
    float*       __restrict__ out)
{
    const int tid = blockIdx.x * blockDim.x + threadIdx.x;  // [0, E_NUM/EPT)

    const float R_RANGE = 30.0f - 0.5f;
    const float BINS    = 512.0f;
    const float BEAMS   = 512.0f;

    // streaming index loads: non-temporal (don't evict the gather tables)
    const i32x4 s4 = __builtin_nontemporal_load((const i32x4*)src_idx + tid);
    const i32x4 t4 = __builtin_nontemporal_load((const i32x4*)tgt_idx + tid);
    const i32x4 p4 = __builtin_nontemporal_load((const i32x4*)patch_idx + tid);
    const int si[EPT] = {s4.x, s4.y, s4.z, s4.w};
    const int ti[EPT] = {t4.x, t4.y, t4.z, t4.w};
    const int pi[EPT] = {p4.x, p4.y, p4.z, p4.w};

    // ---- issue all gathers up front (fused first: longest latency) ----
    f32x4 rec[EPT];
    f32x4 slo[EPT], shi[EPT], tlo[EPT], thi[EPT];
#pragma unroll
    for (int e = 0; e < EPT; ++e) rec[e] = fused[pi[e]];
#pragma unroll
    for (int e = 0; e < EPT; ++e) {
        slo[e] = pose8[2 * si[e]];
        shi[e] = pose8[2 * si[e] + 1];
        tlo[e] = pose8[2 * ti[e]];
        thi[e] = pose8[2 * ti[e] + 1];
    }

    const f32x4 tg01 = __builtin_nontemporal_load((const f32x4*)target + 2 * tid);
    const f32x4 tg23 = __builtin_nontemporal_load((const f32x4*)target + 2 * tid + 1);
    const float tgr[EPT]  = {tg01.x, tg01.z, tg23.x, tg23.z};
    const float tgth[EPT] = {tg01.y, tg01.w, tg23.y, tg23.w};

    float res[2 * EPT];
#pragma unroll
    for (int e = 0; e < EPT; ++e) {
        // local cartesian already precomputed in prep
        const float vx = rec[e].x;
        const float vy = rec[e].y;
        const float vz = rec[e].z;

        float gx, gy, gz;
        quatrot(slo[e].w, shi[e].x, shi[e].y, shi[e].z, vx, vy, vz, gx, gy, gz);
        gx += slo[e].x; gy += slo[e].y; gz += slo[e].z;

        float lx, ly, lz;
        quatrot(-tlo[e].w, -thi[e].x, -thi[e].y, thi[e].z,
                gx - tlo[e].x, gy - tlo[e].y, gz - tlo[e].z, lx, ly, lz);

        const float rr  = sqrtf(lx * lx + ly * ly + lz * lz);
        const float tth = atan2f(ly, lx);
        res[2 * e]     = (rr  - tgr[e])  / R_RANGE * BINS;
        res[2 * e + 1] = (tth - tgth[e]) / FOV_H * BEAMS;
    }

    const f32x4 o0 = {res[0], res[1], res[2], res[3]};
    const f32x4 o1 = {res[4], res[5], res[6], res[7]};
    __builtin_nontemporal_store(o0, (f32x4*)out + 2 * tid);
    __builtin_nontemporal_store(o1, (f32x4*)out + 2 * tid + 1);
}

extern "C" void kernel_launch(void* const* d_in, const int* in_sizes, int n_in,
                              void* d_out, int out_size, void* d_ws, size_t ws_size,
                              hipStream_t stream) {
    const float* poses        = (const float*)d_in[0];
    const float* init_poses   = (const float*)d_in[1];
    const float* patch_coords = (const float*)d_in[2];
    const float* elev         = (const float*)d_in[3];
    const float* init_elev    = (const float*)d_in[4];
    const float* target       = (const float*)d_in[5];
    const int*   src_idx      = (const int*)d_in[6];
    const int*   tgt_idx      = (const int*)d_in[7];
    const int*   patch_idx    = (const int*)d_in[8];
    float*       out          = (float*)d_out;

    f32x4* fused = (f32x4*)d_ws;                                   // 67.1 MB
    f32x4* pose8 = (f32x4*)((char*)d_ws + (size_t)E_NUM * 16);     // 256 KB

    fuse_prep<<<E_NUM / 256, 256, 0, stream>>>((const f32x2*)patch_coords, elev,
                                               init_elev, poses, init_poses,
                                               fused, pose8, out);

    const int block = 256;
    const int grid  = E_NUM / (block * EPT);    // 4096
    ba_main<<<grid, block, 0, stream>>>(fused, pose8, target, src_idx, tgt_idx,
                                        patch_idx, out);
}

// Round 6
// 261.910 us; speedup vs baseline: 1.1322x; 1.0349x over previous
//
#include <hip/hip_runtime.h>
#include <math.h>

#define P_NUM 8192
#define E_NUM 4194304

#define FOV_H 2.0943951f

typedef float f32x4 __attribute__((ext_vector_type(4)));
typedef float f32x2 __attribute__((ext_vector_type(2)));

// ---------- prep: one record per thread, every access coalesced.
// fused[t] = (vx,vy,vz,0) local cartesian; elev residual scalar;
// pose8 padding + pose residual folded into low-index threads.
__global__ __launch_bounds__(256) void fuse_prep(const f32x2* __restrict__ patch_coords,
                                                 const float* __restrict__ elev,
                                                 const float* __restrict__ init_elev,
                                                 const float* __restrict__ poses,
                                                 const float* __restrict__ init_poses,
                                                 f32x4* __restrict__ fused,
                                                 f32x4* __restrict__ pose8,
                                                 float* __restrict__ out) {
    const int t = blockIdx.x * blockDim.x + threadIdx.x;   // [0, E_NUM)

    const f32x2 pc = __builtin_nontemporal_load(patch_coords + t);   // (r, theta)
    const float e  = __builtin_nontemporal_load(elev + t);
    const float ie = __builtin_nontemporal_load(init_elev + t);

    const float r  = pc.x;
    const float th = pc.y;
    // identical op order to previous version
    const float cp = cosf(e),  sp = sinf(e);
    const float ct = cosf(th), st = sinf(th);
    const float rcp = r * cp;
    fused[t] = (f32x4){rcp * ct, rcp * st, r * sp, 0.0f};   // cached store: ba_main re-reads

    __builtin_nontemporal_store(e - ie, out + 2 * E_NUM + 7 * P_NUM + t);

    // pose work folded in: first P_NUM threads pad poses, first 14336 do residual
    if (t < P_NUM) {
        const float* s = poses + 7 * t;
        pose8[2 * t]     = (f32x4){s[0], s[1], s[2], s[3]};  // tx ty tz qx
        pose8[2 * t + 1] = (f32x4){s[4], s[5], s[6], 0.0f};  // qy qz qw pad
    }
    if (t < (7 * P_NUM) / 4) {
        const f32x4 pa = ((const f32x4*)poses)[t];
        const f32x4 pb = ((const f32x4*)init_poses)[t];
        const f32x4 r2 = {pa.x - pb.x, pa.y - pb.y, pa.z - pb.z, pa.w - pb.w};
        __builtin_nontemporal_store(r2, (f32x4*)(out + 2 * E_NUM) + t);
    }
}

__device__ __forceinline__ void quatrot(float ux, float uy, float uz, float uw,
                                        float vx, float vy, float vz,
                                        float& ox, float& oy, float& oz) {
    float tqx = 2.0f * (uy * vz - uz * vy);
    float tqy = 2.0f * (uz * vx - ux * vz);
    float tqz = 2.0f * (ux * vy - uy * vx);
    ox = vx + uw * tqx + (uy * tqz - uz * tqy);
    oy = vy + uw * tqy + (uz * tqx - ux * tqz);
    oz = vz + uw * tqz + (ux * tqy - uy * tqx);
}

// EPT=1: max thread-level parallelism. Per-wave MLP is compiler-pinned at ~5
// outstanding loads (VGPR 32-36 regardless of launch bounds), so total
// outstanding requests scale with RESIDENT WAVES, not per-thread edges.
// One edge per thread -> 4x the waves, minimal VGPR, shortest dep chain.
__global__ __launch_bounds__(256) void ba_main(
    const f32x4* __restrict__ fused,   // E_NUM x (vx,vy,vz,pad), ws
    const f32x4* __restrict__ pose8,   // ws
    const f32x2* __restrict__ target,  // E_NUM x (r,theta)
    const int*   __restrict__ src_idx,
    const int*   __restrict__ tgt_idx,
    const int*   __restrict__ patch_idx,
    f32x2*       __restrict__ out)
{
    const int tid = blockIdx.x * blockDim.x + threadIdx.x;  // [0, E_NUM)

    const float R_RANGE = 30.0f - 0.5f;
    const float BINS    = 512.0f;
    const float BEAMS   = 512.0f;

    // streaming index loads (coalesced 4B/lane); nontemporal: keep L2 for tables
    const int pi = __builtin_nontemporal_load(patch_idx + tid);
    const int si = __builtin_nontemporal_load(src_idx + tid);
    const int ti = __builtin_nontemporal_load(tgt_idx + tid);

    // all 5 gathers issue together (fused first: longest latency)
    const f32x4 rec = fused[pi];
    const f32x4 slo = pose8[2 * si];
    const f32x4 shi = pose8[2 * si + 1];
    const f32x4 tlo = pose8[2 * ti];
    const f32x4 thi = pose8[2 * ti + 1];
    const f32x2 tg  = __builtin_nontemporal_load(target + tid);

    const float vx = rec.x;
    const float vy = rec.y;
    const float vz = rec.z;

    float gx, gy, gz;
    quatrot(slo.w, shi.x, shi.y, shi.z, vx, vy, vz, gx, gy, gz);
    gx += slo.x; gy += slo.y; gz += slo.z;

    float lx, ly, lz;
    quatrot(-tlo.w, -thi.x, -thi.y, thi.z,
            gx - tlo.x, gy - tlo.y, gz - tlo.z, lx, ly, lz);

    const float rr  = sqrtf(lx * lx + ly * ly + lz * lz);
    const float tth = atan2f(ly, lx);

    const f32x2 o = {(rr  - tg.x) / R_RANGE * BINS,
                     (tth - tg.y) / FOV_H  * BEAMS};
    __builtin_nontemporal_store(o, out + tid);
}

extern "C" void kernel_launch(void* const* d_in, const int* in_sizes, int n_in,
                              void* d_out, int out_size, void* d_ws, size_t ws_size,
                              hipStream_t stream) {
    const float* poses        = (const float*)d_in[0];
    const float* init_poses   = (const float*)d_in[1];
    const float* patch_coords = (const float*)d_in[2];
    const float* elev         = (const float*)d_in[3];
    const float* init_elev    = (const float*)d_in[4];
    const float* target       = (const float*)d_in[5];
    const int*   src_idx      = (const int*)d_in[6];
    const int*   tgt_idx      = (const int*)d_in[7];
    const int*   patch_idx    = (const int*)d_in[8];
    float*       out          = (float*)d_out;

    f32x4* fused = (f32x4*)d_ws;                                   // 67.1 MB
    f32x4* pose8 = (f32x4*)((char*)d_ws + (size_t)E_NUM * 16);     // 256 KB

    fuse_prep<<<E_NUM / 256, 256, 0, stream>>>((const f32x2*)patch_coords, elev,
                                               init_elev, poses, init_poses,
                                               fused, pose8, out);

    ba_main<<<E_NUM / 256, 256, 0, stream>>>(fused, pose8, (const f32x2*)target,
                                             src_idx, tgt_idx, patch_idx,
                                             (f32x2*)out);
}